// Round 7
// baseline (58.354 us; speedup 1.0000x reference)
//
#include <hip/hip_runtime.h>

#define SPATIAL_SCALE 0.0625f
#define PH 7
#define PW 7
#define SR 2
#define C_TOTAL 1024
#define NXCD 8
#define NPOS (PH * PW)     // 49

typedef float f4v __attribute__((ext_vector_type(4), aligned(8)));
typedef float f4a __attribute__((ext_vector_type(4), aligned(16)));

// Block = one (roi n, 64-channel superchunk). blockIdx&7 -> XCD -> 128-ch
// slab, so each XCD's L2 only sees 2.56 MB of input (R4: FETCH 348->10 MB).
// R6: full-lane mapping t -> (s=t%49, g=t/49), 245/256 lanes compute.
// R7: branchless 3-row loads (row2 clamped, weight 0 when unused) + manual
// 1-deep software pipeline so 3 loads stay in flight per wave (latency hide).
__global__ __launch_bounds__(256) void roi_align_kernel(
    const float* __restrict__ data,   // (B, C, H, W)
    const float* __restrict__ rois,   // (N, 5)
    float* __restrict__ out,          // (N, C, PH, PW)
    int H, int W, int N)
{
    __shared__ __align__(16) float so[64 * NPOS];   // 12544 B

    int i   = blockIdx.x;
    int xcd = i & (NXCD - 1);
    int j   = i >> 3;                 // [0, 2N)
    int scl = (j >= N) ? 1 : 0;       // superchunk-local (2 per XCD)
    int n   = j - scl * N;
    int superchunk = xcd * 2 + scl;   // [0,16): 64 channels each

    int t = threadIdx.x;
    bool active = (t < 5 * NPOS);     // 245 compute lanes
    int tt = active ? t : 0;
    int s  = tt % NPOS;
    int g  = tt / NPOS;               // channel group 0..4
    int cbase = g * 13;               // g=4 -> 52
    int cnt = (g < 4) ? 13 : 12;      // 4*13 + 12 = 64
    int pw = s % PW;
    int ph = s / PW;

    if (active) {
        const float* roi = rois + n * 5;
        int   b  = (int)roi[0];
        float x1 = roi[1] * SPATIAL_SCALE;
        float y1 = roi[2] * SPATIAL_SCALE;
        float x2 = roi[3] * SPATIAL_SCALE;
        float y2 = roi[4] * SPATIAL_SCALE;
        float roi_w = fmaxf(x2 - x1, 1.0f);
        float roi_h = fmaxf(y2 - y1, 1.0f);
        float bin_w = roi_w * (1.0f / PW);
        float bin_h = roi_h * (1.0f / PH);

        // ---- x: 2 samples collapse into a 4-wide even-aligned window ----
        float xc0 = x1 + ((float)(pw * SR + 0) + 0.5f) * bin_w * (1.0f / SR);
        float xc1 = x1 + ((float)(pw * SR + 1) + 0.5f) * bin_w * (1.0f / SR);
        float vx0 = (xc0 >= -1.0f && xc0 <= (float)W) ? 1.0f : 0.0f;
        float vx1 = (xc1 >= -1.0f && xc1 <= (float)W) ? 1.0f : 0.0f;
        float xcl0 = fminf(fmaxf(xc0, 0.0f), (float)(W - 1));
        float xcl1 = fminf(fmaxf(xc1, 0.0f), (float)(W - 1));
        int xl0 = min(max((int)floorf(xcl0), 0), W - 2);
        int xl1 = min(max((int)floorf(xcl1), 0), W - 2);
        float lx0 = xcl0 - (float)xl0, hx0 = 1.0f - lx0;
        float lx1 = xcl1 - (float)xl1, hx1 = 1.0f - lx1;

        int xb = min(xl0 & ~1, W - 4);
        int p0 = xl0 - xb;               // {0,1}
        int p1 = xl1 - xb;               // {0,1,2}; p1+1 <= 3

        float w4[4];
        #pragma unroll
        for (int k = 0; k < 4; ++k) {
            float a = (p0 == k) ? hx0 : ((p0 + 1 == k) ? lx0 : 0.0f);
            float c = (p1 == k) ? hx1 : ((p1 + 1 == k) ? lx1 : 0.0f);
            w4[k] = vx0 * a + vx1 * c;
        }

        // ---- y: 2 samples -> 3-row window (yl1-yl0 in {0,1}) ----
        float yc0 = y1 + ((float)(ph * SR + 0) + 0.5f) * bin_h * (1.0f / SR);
        float yc1 = y1 + ((float)(ph * SR + 1) + 0.5f) * bin_h * (1.0f / SR);
        float vy0 = (yc0 >= -1.0f && yc0 <= (float)H) ? 1.0f : 0.0f;
        float vy1 = (yc1 >= -1.0f && yc1 <= (float)H) ? 1.0f : 0.0f;
        float ycl0 = fminf(fmaxf(yc0, 0.0f), (float)(H - 1));
        float ycl1 = fminf(fmaxf(yc1, 0.0f), (float)(H - 1));
        int yl0 = min(max((int)floorf(ycl0), 0), H - 2);
        int yl1 = min(max((int)floorf(ycl1), 0), H - 2);
        float ly0 = ycl0 - (float)yl0, hy0 = 1.0f - ly0;
        float ly1 = ycl1 - (float)yl1, hy1 = 1.0f - ly1;

        float wy0 = 0.25f * vy0 * hy0;
        float wy1 = 0.25f * vy0 * ly0;
        float wy2 = 0.25f * vy1 * hy1;
        float wy3 = 0.25f * vy1 * ly1;

        int q = yl1 - yl0;               // 0 or 1
        float wr0 = wy0 + ((q == 0) ? wy2 : 0.0f);
        float wr1 = wy1 + ((q == 0) ? wy3 : wy2);
        float wr2 = (q == 0) ? 0.0f : wy3;

        int row0 = yl0;
        int row2 = min(yl0 + 2, H - 1);  // clamped; weight 0 when clamp engaged

        float wv[3][4];
        #pragma unroll
        for (int k = 0; k < 4; ++k) {
            wv[0][k] = wr0 * w4[k];
            wv[1][k] = wr1 * w4[k];
            wv[2][k] = wr2 * w4[k];
        }

        // ---- channel loop: 3 pipelined vector loads + 12 FMA per output ----
        int c0 = superchunk * 64 + cbase;
        const int HW = H * W;
        unsigned slab = (unsigned)(b * C_TOTAL + c0) * (unsigned)HW;
        unsigned o0 = slab + (unsigned)(row0 * W + xb);
        unsigned o1 = o0 + (unsigned)W;
        unsigned o2 = slab + (unsigned)(row2 * W + xb);
        int ldsbase = cbase * NPOS + s;

        f4v a0 = *(const f4v*)(data + o0);
        f4v a1 = *(const f4v*)(data + o1);
        f4v a2 = *(const f4v*)(data + o2);

        int jj = 0;
        #pragma unroll 4
        for (; jj < cnt - 1; ++jj) {
            o0 += HW; o1 += HW; o2 += HW;
            f4v b0 = *(const f4v*)(data + o0);   // prefetch next channel
            f4v b1 = *(const f4v*)(data + o1);
            f4v b2 = *(const f4v*)(data + o2);
            float acc = wv[0][0] * a0.x;
            acc += wv[0][1] * a0.y;  acc += wv[0][2] * a0.z;  acc += wv[0][3] * a0.w;
            acc += wv[1][0] * a1.x;  acc += wv[1][1] * a1.y;
            acc += wv[1][2] * a1.z;  acc += wv[1][3] * a1.w;
            acc += wv[2][0] * a2.x;  acc += wv[2][1] * a2.y;
            acc += wv[2][2] * a2.z;  acc += wv[2][3] * a2.w;
            so[ldsbase + jj * NPOS] = acc;
            a0 = b0; a1 = b1; a2 = b2;
        }
        {
            float acc = wv[0][0] * a0.x;
            acc += wv[0][1] * a0.y;  acc += wv[0][2] * a0.z;  acc += wv[0][3] * a0.w;
            acc += wv[1][0] * a1.x;  acc += wv[1][1] * a1.y;
            acc += wv[1][2] * a1.z;  acc += wv[1][3] * a1.w;
            acc += wv[2][0] * a2.x;  acc += wv[2][1] * a2.y;
            acc += wv[2][2] * a2.z;  acc += wv[2][3] * a2.w;
            so[ldsbase + jj * NPOS] = acc;
        }
    }

    __syncthreads();

    // ---- coalesced b128 writeback of the block's contiguous 12544B ----
    unsigned base = (unsigned)(n * C_TOTAL + superchunk * 64) * NPOS;
    f4a* dst = (f4a*)(out + base);
    const f4a* src = (const f4a*)so;
    int tid = threadIdx.x;
    // 64*49/4 = 784 f4 elements = 3*256 + 16
    dst[tid]       = src[tid];
    dst[256 + tid] = src[256 + tid];
    dst[512 + tid] = src[512 + tid];
    if (tid < 16) dst[768 + tid] = src[768 + tid];
}

extern "C" void kernel_launch(void* const* d_in, const int* in_sizes, int n_in,
                              void* d_out, int out_size, void* d_ws, size_t ws_size,
                              hipStream_t stream) {
    const float* data = (const float*)d_in[0];
    const float* rois = (const float*)d_in[1];
    float* out = (float*)d_out;

    const int H = 50, W = 50;
    const int N = in_sizes[1] / 5;
    const int nblocks = N * 16;   // 16 superchunks x N rois; blockIdx&7 = XCD

    dim3 block(256);
    dim3 grid(nblocks);
    roi_align_kernel<<<grid, block, 0, stream>>>(data, rois, out, H, W, N);
}